// Round 2
// baseline (373.555 us; speedup 1.0000x reference)
//
#include <hip/hip_runtime.h>
#include <hip/hip_bf16.h>
#include <stdint.h>

// Problem constants
#define NN 8192
#define CC 16
#define RPB 64              // rows per block (4 waves x 16 rows)
#define COLSPLIT 16         // column splits -> grid = 128 * 16 = 2048 blocks
#define CPB (NN / COLSPLIT) // 512 columns per block
#define NCHUNK (NN / 32)    // 256 K-chunks of 32 columns
#define ITERS (CPB / 32)    // 16 K-iterations per block
#define NBLK ((NN / RPB) * COLSPLIT)  // 2048

typedef __attribute__((ext_vector_type(8))) short bf16x8;
typedef __attribute__((ext_vector_type(4))) float f32x4;
typedef __attribute__((ext_vector_type(4))) unsigned int u32x4;

// ws layout:
//   +8192        B-fragment table: [2 pass][256 chunk][64 lane] x 16 B = 512 KB
//   +1 MB        quad_p[NBLK]  (f64, 16 KB)
//   +1 MB+32 KB  cnt_p[NBLK]   (i32, 8 KB)
//   +1 MB+64 KB  dh_p[NBLK*16] (f64, 256 KB)

__device__ __forceinline__ unsigned short f32_to_bf16(float f) {
  unsigned int u = __float_as_uint(f);
  u = u + 0x7FFFu + ((u >> 16) & 1u);  // RNE
  return (unsigned short)(u >> 16);
}
__device__ __forceinline__ float bf16_to_f32(unsigned short h) {
  return __uint_as_float(((unsigned int)h) << 16);
}

// Pre-pack H (hi/lo bf16 split) into MFMA B-fragment order:
// B[k][n]: n = lane&15, k = (lane>>4)*8 + idx  (16x16x32 bf16)
__global__ void prep_btab(const float* __restrict__ H, u32x4* __restrict__ btab) {
  int t = blockIdx.x * blockDim.x + threadIdx.x;  // 0 .. 2*256*64-1
  int lane = t & 63;
  int chunk = (t >> 6) & (NCHUNK - 1);
  int pass = t >> 14;  // 0 = hi, 1 = lo
  int c = lane & 15, q = lane >> 4;
  int j0 = chunk * 32 + q * 8;
  unsigned int w[4];
#pragma unroll
  for (int p = 0; p < 4; ++p) {
    unsigned int r = 0;
#pragma unroll
    for (int e = 0; e < 2; ++e) {
      float x = H[(size_t)(j0 + 2 * p + e) * CC + c];
      unsigned short hb = f32_to_bf16(x);
      unsigned short bits = hb;
      if (pass) bits = f32_to_bf16(x - bf16_to_f32(hb));
      r |= ((unsigned int)bits) << (16 * e);
    }
    w[p] = r;
  }
  u32x4 o; o.x = w[0]; o.y = w[1]; o.z = w[2]; o.w = w[3];
  btab[t] = o;
}

__global__ __launch_bounds__(256, 4) void main_k(
    const float* __restrict__ A, const float* __restrict__ H,
    const u32x4* __restrict__ btab,
    double* __restrict__ quad_p, int* __restrict__ cnt_p,
    double* __restrict__ dh_p) {
  __shared__ float sdH[4][16];
  __shared__ float squad[4];
  __shared__ int scnt[4];

  int tid = threadIdx.x;
  int wave = tid >> 6, lane = tid & 63;
  int rb = blockIdx.x / COLSPLIT, cb = blockIdx.x % COLSPLIT;
  int m = lane & 15, q = lane >> 4;
  int row0 = rb * RPB + wave * 16;
  int col0 = cb * CPB;

  // A fragment source: A[row0+m][col0 + q*8 + ...], 2x float4 per chunk
  const float* arow = A + (size_t)(row0 + m) * NN + col0 + q * 8;
  int chunk0 = col0 >> 5;
  const u32x4* bth = btab + (size_t)chunk0 * 64 + lane;
  const u32x4* btl = bth + (size_t)NCHUNK * 64;

  f32x4 acc_h = {0.f, 0.f, 0.f, 0.f};
  f32x4 acc_l = {0.f, 0.f, 0.f, 0.f};
  int cnt = 0;

#pragma unroll 2
  for (int it = 0; it < ITERS; ++it) {
    f32x4 a0 = *(const f32x4*)(arow + it * 32);
    f32x4 a1 = *(const f32x4*)(arow + it * 32 + 4);
    u32x4 bh = bth[it * 64];
    u32x4 bl = btl[it * 64];
    // threshold A>0 -> packed bf16 {1.0, 0.0}, A-frag layout k = q*8+idx
    unsigned int p0 = (a0.x > 0.f ? 0x3F80u : 0u) | (a0.y > 0.f ? 0x3F800000u : 0u);
    unsigned int p1 = (a0.z > 0.f ? 0x3F80u : 0u) | (a0.w > 0.f ? 0x3F800000u : 0u);
    unsigned int p2 = (a1.x > 0.f ? 0x3F80u : 0u) | (a1.y > 0.f ? 0x3F800000u : 0u);
    unsigned int p3 = (a1.z > 0.f ? 0x3F80u : 0u) | (a1.w > 0.f ? 0x3F800000u : 0u);
    cnt += __popc(p0 & 0x00800080u) + __popc(p1 & 0x00800080u) +
           __popc(p2 & 0x00800080u) + __popc(p3 & 0x00800080u);
    u32x4 af; af.x = p0; af.y = p1; af.z = p2; af.w = p3;
    bf16x8 afrag = __builtin_bit_cast(bf16x8, af);
    acc_h = __builtin_amdgcn_mfma_f32_16x16x32_bf16(afrag, __builtin_bit_cast(bf16x8, bh), acc_h, 0, 0, 0);
    acc_l = __builtin_amdgcn_mfma_f32_16x16x32_bf16(afrag, __builtin_bit_cast(bf16x8, bl), acc_l, 0, 0, 0);
  }

  // C/D layout (16x16): col c = lane&15, row = q*4 + reg
  f32x4 af = acc_h + acc_l;  // r_i[c] partial (this wave's column stripe)

  // dH partial: sum r over this wave's 16 rows, per class c = lane&15
  float rowsum = af.x + af.y + af.z + af.w;
  rowsum += __shfl_xor(rowsum, 16, 64);
  rowsum += __shfl_xor(rowsum, 32, 64);

  // quad partial: sum_i H[i][c] * r_i[c]
  const float* hr = H + (size_t)(row0 + q * 4) * CC + m;
  float qp = af.x * hr[0] + af.y * hr[CC] + af.z * hr[2 * CC] + af.w * hr[3 * CC];
#pragma unroll
  for (int d = 1; d < 64; d <<= 1) qp += __shfl_xor(qp, d, 64);
#pragma unroll
  for (int d = 1; d < 64; d <<= 1) cnt += __shfl_xor(cnt, d, 64);

  if (lane < 16) sdH[wave][lane] = rowsum;
  if (lane == 0) { squad[wave] = qp; scnt[wave] = cnt; }
  __syncthreads();
  int bid = blockIdx.x;
  if (tid < 16) {
    dh_p[(size_t)bid * 16 + tid] =
        (double)(sdH[0][tid] + sdH[1][tid] + sdH[2][tid] + sdH[3][tid]);
  } else if (tid == 16) {
    quad_p[bid] = (double)(squad[0] + squad[1] + squad[2] + squad[3]);
  } else if (tid == 17) {
    cnt_p[bid] = scnt[0] + scnt[1] + scnt[2] + scnt[3];
  }
}

__global__ __launch_bounds__(256) void reduce_finalize(
    const double* __restrict__ quad_p, const int* __restrict__ cnt_p,
    const double* __restrict__ dh_p, float* __restrict__ out) {
  __shared__ double sq[4];
  __shared__ long long sc[4];
  __shared__ double sdh[4][16];
  int t = threadIdx.x;
  int wave = t >> 6, lane = t & 63;

  double q = 0.0;
  long long c = 0;
  double dh[16];
#pragma unroll
  for (int k = 0; k < 16; ++k) dh[k] = 0.0;

  for (int b = t; b < NBLK; b += 256) {
    q += quad_p[b];
    c += (long long)cnt_p[b];
#pragma unroll
    for (int k = 0; k < 16; ++k) dh[k] += dh_p[(size_t)b * 16 + k];
  }
#pragma unroll
  for (int d = 1; d < 64; d <<= 1) {
    q += __shfl_xor(q, d, 64);
    c += __shfl_xor(c, d, 64);
#pragma unroll
    for (int k = 0; k < 16; ++k) dh[k] += __shfl_xor(dh[k], d, 64);
  }
  if (lane == 0) {
    sq[wave] = q; sc[wave] = c;
#pragma unroll
    for (int k = 0; k < 16; ++k) sdh[wave][k] = dh[k];
  }
  __syncthreads();
  if (t == 0) {
    double Q = sq[0] + sq[1] + sq[2] + sq[3];
    double S = (double)(sc[0] + sc[1] + sc[2] + sc[3]);
    double D2 = 0.0;
#pragma unroll
    for (int k = 0; k < 16; ++k) {
      double v = sdh[0][k] + sdh[1][k] + sdh[2][k] + sdh[3][k];
      D2 += v * v;
    }
    out[0] = (float)((Q - D2 / S) / S);
  }
}

extern "C" void kernel_launch(void* const* d_in, const int* in_sizes, int n_in,
                              void* d_out, int out_size, void* d_ws, size_t ws_size,
                              hipStream_t stream) {
  const float* H = (const float*)d_in[0];
  const float* A = (const float*)d_in[1];
  if (n_in >= 2 && in_sizes[0] != NN * CC) {  // defensive: input order
    H = (const float*)d_in[1];
    A = (const float*)d_in[0];
  }
  float* out = (float*)d_out;
  char* ws = (char*)d_ws;
  u32x4* btab = (u32x4*)(ws + 8192);
  double* quad_p = (double*)(ws + (1 << 20));
  int* cnt_p = (int*)(ws + (1 << 20) + (32 << 10));
  double* dh_p = (double*)(ws + (1 << 20) + (64 << 10));

  prep_btab<<<(2 * NCHUNK * 64) / 256, 256, 0, stream>>>(H, btab);
  main_k<<<NBLK, 256, 0, stream>>>(A, H, btab, quad_p, cnt_p, dh_p);
  reduce_finalize<<<1, 256, 0, stream>>>(quad_p, cnt_p, dh_p, out);
}